// Round 17
// baseline (129.619 us; speedup 1.0000x reference)
//
#include <hip/hip_runtime.h>
#include <hip/hip_bf16.h>

#define NQ   14
#define DIM  16384      // 2^14
#define BLK  1024
#define WMUL 0.6324555320336759f  // sqrt(2/5)

typedef float v2f __attribute__((ext_vector_type(2)));
// constant-address-space pointer: forces s_load (scalar cache, SGPR dest)
typedef const __attribute__((address_space(4))) v2f* cgp;
typedef const __attribute__((address_space(4))) float* cfp;

struct C2 { float x, y; };  // build-time only
__device__ inline C2 cmulc(C2 a, C2 b){ return C2{a.x*b.x - a.y*b.y, a.x*b.y + a.y*b.x}; }
__device__ inline C2 caddc(C2 a, C2 b){ return C2{a.x+b.x, a.y+b.y}; }
__device__ inline void mm2(const C2* a, const C2* b, C2* o) {
    o[0] = caddc(cmulc(a[0],b[0]), cmulc(a[1],b[2]));
    o[1] = caddc(cmulc(a[0],b[1]), cmulc(a[1],b[3]));
    o[2] = caddc(cmulc(a[2],b[0]), cmulc(a[3],b[2]));
    o[3] = caddc(cmulc(a[2],b[1]), cmulc(a[3],b[3]));
}
__device__ inline void build_gate(int ty, float t, C2* g) {
    float sn, cs;
    __sincosf(0.5f * t, &sn, &cs);
    if (ty == 0) {        // rx
        g[0] = C2{cs, 0.f}; g[1] = C2{0.f, -sn};
        g[2] = C2{0.f, -sn}; g[3] = C2{cs, 0.f};
    } else if (ty == 1) { // ry
        g[0] = C2{cs, 0.f}; g[1] = C2{-sn, 0.f};
        g[2] = C2{sn, 0.f}; g[3] = C2{cs, 0.f};
    } else {              // rz
        g[0] = C2{cs, -sn}; g[1] = C2{0.f, 0.f};
        g[2] = C2{0.f, 0.f}; g[3] = C2{cs, sn};
    }
}
__device__ const int TYPES[5][3] = {
    {0,1,2},  // XYZ
    {1,2,1},  // YZY
    {2,1,0},  // ZYX
    {0,2,0},  // XZX
    {1,2,1},  // YZY
};

// ---- prep kernel: 70 fused gates (packed form) + absorbed observable -> d_ws.
__global__ void prep_kernel(const float* __restrict__ w, v2f* __restrict__ gg) {
    const int tid = threadIdx.x;
    if (tid < 5 * NQ) {
        const int li = tid / NQ, q = tid % NQ;
        C2 M[4], G[4], T[4];
        #pragma unroll
        for (int j = 0; j < 3; ++j) {
            float t = w[3 * NQ * li + 3 * q + j] * WMUL;
            build_gate(TYPES[li][j], t, G);
            if (j == 0) { M[0]=G[0]; M[1]=G[1]; M[2]=G[2]; M[3]=G[3]; }
            else { mm2(G, M, T); M[0]=T[0]; M[1]=T[1]; M[2]=T[2]; M[3]=T[3]; }
        }
        v2f* gb = &gg[tid * 8];
        #pragma unroll
        for (int k = 0; k < 4; ++k) {
            gb[k * 2 + 0] = v2f{ M[k].x, M[k].x};
            gb[k * 2 + 1] = v2f{-M[k].y, M[k].y};
        }
        // absorbed observable M1 = M† Z M for the layer-5 qubit-0 rotation
        if (tid == 4 * NQ + 0) {
            float* mm = (float*)&gg[5 * NQ * 8];
            mm[0] = M[0].x*M[0].x + M[0].y*M[0].y - (M[2].x*M[2].x + M[2].y*M[2].y);
            mm[1] = M[1].x*M[1].x + M[1].y*M[1].y - (M[3].x*M[3].x + M[3].y*M[3].y);
            mm[2] = (M[0].x*M[1].x + M[0].y*M[1].y) - (M[2].x*M[3].x + M[2].y*M[3].y);
            mm[3] = (M[0].x*M[1].y - M[0].y*M[1].x) - (M[2].x*M[3].y - M[2].y*M[3].x);
        }
    }
}

// bank-conflict swizzle; GF(2)-LINEAR: slotf(a|b) = slotf(a)^slotf(b) for disjoint a,b
__device__ inline constexpr uint32_t slotf(uint32_t i){
    return i ^ (((i>>4) ^ (i>>8) ^ (i>>12)) & 15u);
}
template<int B> __device__ inline uint32_t ins0(uint32_t t){
    return ((t & ~((1u<<B)-1u)) << 1) | (t & ((1u<<B)-1u));
}
template<int B0,int B1,int B2,int B3> __device__ inline uint32_t expand4(uint32_t t){
    return ins0<B3>(ins0<B2>(ins0<B1>(ins0<B0>(t))));
}
template<int B0,int B1,int B2,int B3> __device__ inline constexpr uint32_t rmask4(int r){
    return ((r&1)?(1u<<B0):0u) | ((r&2)?(1u<<B1):0u)
         | ((r&4)?(1u<<B2):0u) | ((r&8)?(1u<<B3):0u);
}

// packed rotation on local bit J over v[16]; coefficients come from SGPRs
// (s_load via constant AS) and feed v_pk_* as the scalar operand.
template<int J>
__device__ inline void rot16(v2f* v, cgp g){
    const v2f a00=g[0], b00=g[1], a01=g[2], b01=g[3];
    const v2f a10=g[4], b10=g[5], a11=g[6], b11=g[7];
    #pragma unroll
    for (int r = 0; r < 16; ++r){
        if (!(r & (1 << J))) {
            v2f x0 = v[r], x1 = v[r | (1 << J)];
            v2f s0 = x0.yx, s1 = x1.yx;
            v2f y0 = a00*x0 + b00*s0 + a01*x1 + b01*s1;
            v2f y1 = a10*x0 + b10*s0 + a11*x1 + b11*s1;
            v[r] = y0; v[r | (1<<J)] = y1;
        }
    }
}
// CNOT both-in-reg (register renaming, free)
template<int C, int T>
__device__ inline void cnot16(v2f* v){
    #pragma unroll
    for (int r = 0; r < 16; ++r){
        if ((r & (1 << C)) && !(r & (1 << T))) {
            v2f tt = v[r]; v[r] = v[r | (1 << T)]; v[r | (1 << T)] = tt;
        }
    }
}
// CNOT with control = thread-index bit, target reg bit T: pure v_cndmask
template<int T>
__device__ inline void cnotSel16(v2f* v, bool c){
    #pragma unroll
    for (int r = 0; r < 16; ++r){
        if (!(r & (1 << T))) {
            v2f lo = v[r], hi = v[r | (1 << T)];
            v[r]          = c ? hi : lo;
            v[r | (1<<T)] = c ? lo : hi;
        }
    }
}

__global__ __launch_bounds__(BLK) void qsim_kernel(
        const float* __restrict__ xr, const float* __restrict__ xi,
        const v2f* __restrict__ gg_, float* __restrict__ out) {
    __shared__ v2f s[DIM];            // 128 KiB statevector (swizzled layout)
    __shared__ float red[BLK / 64];

    const int b   = blockIdx.x;
    const uint32_t tid = threadIdx.x;
    cgp gg = (cgp)(unsigned long long)(const void*)gg_;

    const float* xrb = xr + (size_t)b * DIM;
    const float* xib = xi + (size_t)b * DIM;

    // qubit q <-> bit (13-q).  coefficients: constant AS -> s_load -> SGPR
    #define GMP(li, q) (gg + ((li) * NQ + (q)) * 8)

    // One pass: single sweep, whole state in v[16] (32 VGPRs), no slab loop.
    #define PASS(B0, B1, B2, B3, ...)                                              \
        {                                                                          \
            const uint32_t sb = slotf(expand4<B0,B1,B2,B3>(tid));                  \
            v2f v[16];                                                             \
            _Pragma("unroll")                                                      \
            for (int r = 0; r < 16; ++r)                                           \
                v[r] = s[sb ^ slotf(rmask4<B0,B1,B2,B3>(r))];                      \
            __VA_ARGS__                                                            \
            _Pragma("unroll")                                                      \
            for (int r = 0; r < 16; ++r)                                           \
                s[sb ^ slotf(rmask4<B0,B1,B2,B3>(r))] = v[r];                      \
        }                                                                          \
        __syncthreads();

    float local = 0.f;

    // ---- 4 ring layers, 4 non-overlapping 4-bit windows each; L5 in meas ----
    // W1(10,11,12,13): rot q0(L3),q1(L2),q2(L1),q3(L0) + CN(0,1),(1,2),(2,3)
    // W2(6,7,8,9):     rot q4..q7 + CN(3,4)[sel ctl=b10=t6] + CN(4,5),(5,6),(6,7)
    // W3(2,3,4,5):     rot q8..q11 + CN(7,8)[sel ctl=b6=t2] + CN(8,9),(9,10),(10,11)
    // W4(0,1,12,13):   rot q12(L1),q13(L0) + CN(11,12)[sel ctl=b2=t0]
    //                  + CN(12,13)=<1,0> + CN(13,0)=<0,3>
    //                  (li==3: fuse M1 quadratic form on b13 = L3 pairs, no scatter)
    #pragma unroll 1
    for (int li = 0; li < 4; ++li) {
        // ---- W1 (10,11,12,13) ----
        {
            v2f v[16];
            if (li == 0) {
                #pragma unroll
                for (int r = 0; r < 16; ++r) {
                    uint32_t i = tid | ((uint32_t)r << 10);   // expand4<10..13>(tid)=tid
                    v[r] = v2f{xrb[i], xib[i]};
                }
            } else {
                const uint32_t sb = slotf(expand4<10,11,12,13>(tid));
                #pragma unroll
                for (int r = 0; r < 16; ++r)
                    v[r] = s[sb ^ slotf(rmask4<10,11,12,13>(r))];
            }
            rot16<3>(v, GMP(li,0));
            rot16<2>(v, GMP(li,1));
            rot16<1>(v, GMP(li,2));
            rot16<0>(v, GMP(li,3));
            cnot16<3,2>(v); cnot16<2,1>(v); cnot16<1,0>(v);   // CN(0,1),(1,2),(2,3)
            const uint32_t sb = slotf(expand4<10,11,12,13>(tid));
            #pragma unroll
            for (int r = 0; r < 16; ++r)
                s[sb ^ slotf(rmask4<10,11,12,13>(r))] = v[r];
        }
        __syncthreads();

        // ---- W2 (6,7,8,9): rot q4(b9=L3),q5(b8=L2),q6(b7=L1),q7(b6=L0) ----
        PASS(6,7,8,9,
            rot16<3>(v, GMP(li,4));
            rot16<2>(v, GMP(li,5));
            rot16<1>(v, GMP(li,6));
            rot16<0>(v, GMP(li,7));
            cnotSel16<3>(v, (tid >> 6) & 1u);                 // CN(3,4): ctl q3=b10=t6
            cnot16<3,2>(v); cnot16<2,1>(v); cnot16<1,0>(v);   // CN(4,5),(5,6),(6,7)
        )
        // ---- W3 (2,3,4,5): rot q8(b5=L3),q9(b4=L2),q10(b3=L1),q11(b2=L0) ----
        PASS(2,3,4,5,
            rot16<3>(v, GMP(li,8));
            rot16<2>(v, GMP(li,9));
            rot16<1>(v, GMP(li,10));
            rot16<0>(v, GMP(li,11));
            cnotSel16<3>(v, (tid >> 2) & 1u);                 // CN(7,8): ctl q7=b6=t2
            cnot16<3,2>(v); cnot16<2,1>(v); cnot16<1,0>(v);   // CN(8,9),(9,10),(10,11)
        )
        // ---- W4 (0,1,12,13): rot q12(b1=L1),q13(b0=L0); q1=L2,q0=L3 idle ----
        {
            const uint32_t sb = slotf(expand4<0,1,12,13>(tid));
            v2f v[16];
            #pragma unroll
            for (int r = 0; r < 16; ++r)
                v[r] = s[sb ^ slotf(rmask4<0,1,12,13>(r))];
            rot16<1>(v, GMP(li,12));
            rot16<0>(v, GMP(li,13));
            cnotSel16<1>(v, tid & 1u);                        // CN(11,12): ctl q11=b2=t0
            cnot16<1,0>(v);                                   // CN(12,13)
            cnot16<0,3>(v);                                   // CN(13,0)
            if (li < 3) {
                #pragma unroll
                for (int r = 0; r < 16; ++r)
                    s[sb ^ slotf(rmask4<0,1,12,13>(r))] = v[r];
            } else {
                cfp mm = (cfp)(gg + 5 * NQ * 8);
                const float mA = mm[0], mB = mm[1], mP = mm[2], mQ = mm[3];
                #pragma unroll
                for (int r = 0; r < 8; ++r) {
                    v2f a0 = v[r], a1 = v[r | 8];             // b13=0 / b13=1
                    float n0 = a0.x*a0.x + a0.y*a0.y;
                    float n1 = a1.x*a1.x + a1.y*a1.y;
                    float u  = a0.x*a1.x + a0.y*a1.y;         // Re(conj(a0) a1)
                    float vv = a0.x*a1.y - a0.y*a1.x;         // Im(conj(a0) a1)
                    local += mA*n0 + mB*n1 + 2.f*(mP*u - mQ*vv);
                }
            }
        }
        if (li < 3) __syncthreads();
    }

    #pragma unroll
    for (int off = 32; off > 0; off >>= 1) local += __shfl_down(local, off);
    const int lane = tid & 63, wid = tid >> 6;
    if (lane == 0) red[wid] = local;
    __syncthreads();
    if (tid == 0) {
        float t = 0.f;
        #pragma unroll
        for (int k = 0; k < BLK / 64; ++k) t += red[k];
        out[b] = t;
    }
}

extern "C" void kernel_launch(void* const* d_in, const int* in_sizes, int n_in,
                              void* d_out, int out_size, void* d_ws, size_t ws_size,
                              hipStream_t stream) {
    const float* xr = (const float*)d_in[0];
    const float* xi = (const float*)d_in[1];
    const float* w  = (const float*)d_in[2];
    float* out = (float*)d_out;
    v2f* gg = (v2f*)d_ws;     // 70 gates x 8 v2f + 4 floats meas = 4496 B
    const int B = out_size;   // 512
    prep_kernel<<<1, 128, 0, stream>>>(w, gg);
    qsim_kernel<<<B, BLK, 0, stream>>>(xr, xi, gg, out);
}

// Round 18
// 121.893 us; speedup vs baseline: 1.0634x; 1.0634x over previous
//
#include <hip/hip_runtime.h>
#include <hip/hip_bf16.h>

#define NQ   14
#define DIM  16384      // 2^14
#define BLK  1024
#define WMUL 0.6324555320336759f  // sqrt(2/5)

typedef float v2f __attribute__((ext_vector_type(2)));

struct C2 { float x, y; };  // build-time only
__device__ inline C2 cmulc(C2 a, C2 b){ return C2{a.x*b.x - a.y*b.y, a.x*b.y + a.y*b.x}; }
__device__ inline C2 caddc(C2 a, C2 b){ return C2{a.x+b.x, a.y+b.y}; }
__device__ inline void mm2(const C2* a, const C2* b, C2* o) {
    o[0] = caddc(cmulc(a[0],b[0]), cmulc(a[1],b[2]));
    o[1] = caddc(cmulc(a[0],b[1]), cmulc(a[1],b[3]));
    o[2] = caddc(cmulc(a[2],b[0]), cmulc(a[3],b[2]));
    o[3] = caddc(cmulc(a[2],b[1]), cmulc(a[3],b[3]));
}
__device__ inline void build_gate(int ty, float t, C2* g) {
    float sn, cs;
    __sincosf(0.5f * t, &sn, &cs);
    if (ty == 0) {        // rx
        g[0] = C2{cs, 0.f}; g[1] = C2{0.f, -sn};
        g[2] = C2{0.f, -sn}; g[3] = C2{cs, 0.f};
    } else if (ty == 1) { // ry
        g[0] = C2{cs, 0.f}; g[1] = C2{-sn, 0.f};
        g[2] = C2{sn, 0.f}; g[3] = C2{cs, 0.f};
    } else {              // rz
        g[0] = C2{cs, -sn}; g[1] = C2{0.f, 0.f};
        g[2] = C2{0.f, 0.f}; g[3] = C2{cs, sn};
    }
}
__device__ const int TYPES[5][3] = {
    {0,1,2},  // XYZ
    {1,2,1},  // YZY
    {2,1,0},  // ZYX
    {0,2,0},  // XZX
    {1,2,1},  // YZY
};

// ---- prep kernel: 70 fused gates (packed form) + absorbed observable -> d_ws.
__global__ void prep_kernel(const float* __restrict__ w, v2f* __restrict__ gg) {
    const int tid = threadIdx.x;
    if (tid < 5 * NQ) {
        const int li = tid / NQ, q = tid % NQ;
        C2 M[4], G[4], T[4];
        #pragma unroll
        for (int j = 0; j < 3; ++j) {
            float t = w[3 * NQ * li + 3 * q + j] * WMUL;
            build_gate(TYPES[li][j], t, G);
            if (j == 0) { M[0]=G[0]; M[1]=G[1]; M[2]=G[2]; M[3]=G[3]; }
            else { mm2(G, M, T); M[0]=T[0]; M[1]=T[1]; M[2]=T[2]; M[3]=T[3]; }
        }
        v2f* gb = &gg[tid * 8];
        #pragma unroll
        for (int k = 0; k < 4; ++k) {
            gb[k * 2 + 0] = v2f{ M[k].x, M[k].x};
            gb[k * 2 + 1] = v2f{-M[k].y, M[k].y};
        }
        // absorbed observable M1 = M† Z M for the layer-5 qubit-0 rotation
        if (tid == 4 * NQ + 0) {
            float* mm = (float*)&gg[5 * NQ * 8];
            mm[0] = M[0].x*M[0].x + M[0].y*M[0].y - (M[2].x*M[2].x + M[2].y*M[2].y);
            mm[1] = M[1].x*M[1].x + M[1].y*M[1].y - (M[3].x*M[3].x + M[3].y*M[3].y);
            mm[2] = (M[0].x*M[1].x + M[0].y*M[1].y) - (M[2].x*M[3].x + M[2].y*M[3].y);
            mm[3] = (M[0].x*M[1].y - M[0].y*M[1].x) - (M[2].x*M[3].y - M[2].y*M[3].x);
        }
    }
}

// bank-conflict swizzle; GF(2)-LINEAR: slotf(a|b) = slotf(a)^slotf(b) for disjoint a,b
__device__ inline constexpr uint32_t slotf(uint32_t i){
    return i ^ (((i>>4) ^ (i>>8) ^ (i>>12)) & 15u);
}
template<int B> __device__ inline uint32_t ins0(uint32_t t){
    return ((t & ~((1u<<B)-1u)) << 1) | (t & ((1u<<B)-1u));
}
template<int B0,int B1,int B2> __device__ inline uint32_t expand3(uint32_t t){
    return ins0<B2>(ins0<B1>(ins0<B0>(t)));
}
template<int B0,int B1,int B2> __device__ inline constexpr uint32_t rmask3(int r){
    return ((r&1)?(1u<<B0):0u) | ((r&2)?(1u<<B1):0u) | ((r&4)?(1u<<B2):0u);
}

// Packed rotation on local bit J, guaranteed VOP3P via inline asm (verified R8).
// g layout per gate: {a00,b00,a01,b01,a10,b10,a11,b11} with aXY=(M.x,M.x),
// bXY=(-M.y,M.y). cmul(m,a) = aXY*a + bXY*swz(a); swz folds into op_sel
// (D.lo <- S1.hi, D.hi <- S1.lo): 1 pk_mul + 3 pk_fma per pair-output.
template<int J>
__device__ inline void rot8(v2f* v, const v2f* __restrict__ g){
    const v2f a00=g[0], b00=g[1], a01=g[2], b01=g[3];
    const v2f a10=g[4], b10=g[5], a11=g[6], b11=g[7];
    #pragma unroll
    for (int r = 0; r < 8; ++r){
        if (!(r & (1 << J))) {
            v2f x0 = v[r], x1 = v[r | (1 << J)];
            v2f y0, y1;
            asm("v_pk_mul_f32 %0, %1, %2" : "=v"(y0) : "v"(a00), "v"(x0));
            asm("v_pk_fma_f32 %0, %1, %2, %0 op_sel:[0,1,0] op_sel_hi:[1,0,1]"
                : "+v"(y0) : "v"(b00), "v"(x0));
            asm("v_pk_fma_f32 %0, %1, %2, %0"
                : "+v"(y0) : "v"(a01), "v"(x1));
            asm("v_pk_fma_f32 %0, %1, %2, %0 op_sel:[0,1,0] op_sel_hi:[1,0,1]"
                : "+v"(y0) : "v"(b01), "v"(x1));
            asm("v_pk_mul_f32 %0, %1, %2" : "=v"(y1) : "v"(a10), "v"(x0));
            asm("v_pk_fma_f32 %0, %1, %2, %0 op_sel:[0,1,0] op_sel_hi:[1,0,1]"
                : "+v"(y1) : "v"(b10), "v"(x0));
            asm("v_pk_fma_f32 %0, %1, %2, %0"
                : "+v"(y1) : "v"(a11), "v"(x1));
            asm("v_pk_fma_f32 %0, %1, %2, %0 op_sel:[0,1,0] op_sel_hi:[1,0,1]"
                : "+v"(y1) : "v"(b11), "v"(x1));
            v[r] = y0; v[r | (1<<J)] = y1;
        }
    }
}
// CNOT both-in-reg: control bit C, target bit T (register renaming, free)
template<int C, int T>
__device__ inline void cnot8(v2f* v){
    #pragma unroll
    for (int r = 0; r < 8; ++r){
        if ((r & (1 << C)) && !(r & (1 << T))) {
            v2f tt = v[r]; v[r] = v[r | (1 << T)]; v[r | (1 << T)] = tt;
        }
    }
}
// CNOT with control = thread-index bit, target reg bit T: pure v_cndmask
template<int T>
__device__ inline void cnotSel(v2f* v, bool c){
    #pragma unroll
    for (int r = 0; r < 8; ++r){
        if (!(r & (1 << T))) {
            v2f lo = v[r], hi = v[r | (1 << T)];
            v[r]          = c ? hi : lo;
            v[r | (1<<T)] = c ? lo : hi;
        }
    }
}

__global__ __launch_bounds__(BLK) void qsim_kernel(
        const float* __restrict__ xr, const float* __restrict__ xi,
        const v2f* __restrict__ gg, float* __restrict__ out) {
    __shared__ v2f s[DIM];            // 128 KiB statevector (swizzled layout)
    __shared__ float red[BLK / 64];

    const int b   = blockIdx.x;
    const uint32_t tid = threadIdx.x;

    const float* xrb = xr + (size_t)b * DIM;
    const float* xib = xi + (size_t)b * DIM;

    // qubit q <-> bit (13-q).  coefficients: uniform global (prep kernel output)
    #define GMP(li, q) (&gg[((li) * NQ + (q)) * 8])

    // One pass: 2 sequential slabs (live state = v2f v[8] = 16 VGPRs).
    #define PASS(B0, B1, B2, ...)                                                  \
        _Pragma("unroll 1")                                                        \
        for (uint32_t sl = 0; sl < 2; ++sl) {                                      \
            const uint32_t t  = tid + sl * BLK;                                    \
            const uint32_t sb = slotf(expand3<B0,B1,B2>(t));                       \
            v2f v[8];                                                              \
            _Pragma("unroll")                                                      \
            for (int r = 0; r < 8; ++r)                                            \
                v[r] = s[sb ^ slotf(rmask3<B0,B1,B2>(r))];                         \
            __VA_ARGS__                                                            \
            _Pragma("unroll")                                                      \
            for (int r = 0; r < 8; ++r)                                            \
                s[sb ^ slotf(rmask3<B0,B1,B2>(r))] = v[r];                         \
        }                                                                          \
        __syncthreads();

    float local = 0.f;

    // ---- 4 ring layers, 5 non-overlapping windows each; L5 absorbed in meas ----
    // A(11,12,13): rot q0,q1,q2 + CN(0,1),(1,2)
    // B(8,9,10):   rot q3,q4,q5 + CN(2,3)[sel ctl=t8] + CN(3,4),(4,5)
    // C(5,6,7):    rot q6,q7,q8 + CN(5,6)[sel ctl=t5] + CN(6,7),(7,8)
    // D(2,3,4):    rot q9,q10,q11 + CN(8,9)[sel ctl=t2] + CN(9,10),(10,11)
    // E(0,1,13):   rot q12,q13 + CN(11,12)[sel ctl=t0] + CN(12,13),(13,0)
    //              (li==3: fuse M1 quadratic form on b13 = L2 pairs, no scatter)
    #pragma unroll 1
    for (int li = 0; li < 4; ++li) {
        // ---- A (11,12,13) ----
        #pragma unroll 1
        for (uint32_t sl = 0; sl < 2; ++sl) {
            const uint32_t t = tid + sl * BLK;
            v2f v[8];
            if (li == 0) {
                #pragma unroll
                for (int r = 0; r < 8; ++r) {
                    uint32_t i = t | ((uint32_t)r << 11);   // expand3<11,12,13>(t)=t
                    v[r] = v2f{xrb[i], xib[i]};
                }
            } else {
                const uint32_t sb = slotf(expand3<11,12,13>(t));
                #pragma unroll
                for (int r = 0; r < 8; ++r)
                    v[r] = s[sb ^ slotf(rmask3<11,12,13>(r))];
            }
            rot8<2>(v, GMP(li,0)); rot8<1>(v, GMP(li,1)); rot8<0>(v, GMP(li,2));
            cnot8<2,1>(v); cnot8<1,0>(v);                  // CN(0,1),(1,2)
            const uint32_t sb = slotf(expand3<11,12,13>(t));
            #pragma unroll
            for (int r = 0; r < 8; ++r)
                s[sb ^ slotf(rmask3<11,12,13>(r))] = v[r];
        }
        __syncthreads();

        // ---- B (8,9,10): rot q3(b10),q4(b9),q5(b8) ----
        PASS(8,9,10,
            rot8<2>(v, GMP(li,3)); rot8<1>(v, GMP(li,4)); rot8<0>(v, GMP(li,5));
            cnotSel<2>(v, (t >> 8) & 1u);                  // CN(2,3): ctl q2=b11
            cnot8<2,1>(v); cnot8<1,0>(v);                  // CN(3,4),(4,5)
        )
        // ---- C (5,6,7): rot q6(b7),q7(b6),q8(b5) ----
        PASS(5,6,7,
            rot8<2>(v, GMP(li,6)); rot8<1>(v, GMP(li,7)); rot8<0>(v, GMP(li,8));
            cnotSel<2>(v, (t >> 5) & 1u);                  // CN(5,6): ctl q5=b8
            cnot8<2,1>(v); cnot8<1,0>(v);                  // CN(6,7),(7,8)
        )
        // ---- D (2,3,4): rot q9(b4),q10(b3),q11(b2) ----
        PASS(2,3,4,
            rot8<2>(v, GMP(li,9)); rot8<1>(v, GMP(li,10)); rot8<0>(v, GMP(li,11));
            cnotSel<2>(v, (t >> 2) & 1u);                  // CN(8,9): ctl q8=b5
            cnot8<2,1>(v); cnot8<1,0>(v);                  // CN(9,10),(10,11)
        )
        // ---- E (0,1,13): rot q12(b1=L1),q13(b0=L0) ----
        #pragma unroll 1
        for (uint32_t sl = 0; sl < 2; ++sl) {
            const uint32_t t  = tid + sl * BLK;
            const uint32_t sb = slotf(expand3<0,1,13>(t));
            v2f v[8];
            #pragma unroll
            for (int r = 0; r < 8; ++r)
                v[r] = s[sb ^ slotf(rmask3<0,1,13>(r))];
            rot8<1>(v, GMP(li,12)); rot8<0>(v, GMP(li,13));
            cnotSel<1>(v, t & 1u);                         // CN(11,12): ctl q11=b2
            cnot8<1,0>(v);                                 // CN(12,13)
            cnot8<0,2>(v);                                 // CN(13,0)
            if (li < 3) {
                #pragma unroll
                for (int r = 0; r < 8; ++r)
                    s[sb ^ slotf(rmask3<0,1,13>(r))] = v[r];
            } else {
                const float* mm = (const float*)&gg[5 * NQ * 8];
                const float mA = mm[0], mB = mm[1], mP = mm[2], mQ = mm[3];
                #pragma unroll
                for (int r = 0; r < 4; ++r) {
                    v2f a0 = v[r], a1 = v[r | 4];          // b13=0 / b13=1
                    float n0 = a0.x*a0.x + a0.y*a0.y;
                    float n1 = a1.x*a1.x + a1.y*a1.y;
                    float u  = a0.x*a1.x + a0.y*a1.y;      // Re(conj(a0) a1)
                    float vv = a0.x*a1.y - a0.y*a1.x;      // Im(conj(a0) a1)
                    local += mA*n0 + mB*n1 + 2.f*(mP*u - mQ*vv);
                }
            }
        }
        if (li < 3) __syncthreads();
    }

    #pragma unroll
    for (int off = 32; off > 0; off >>= 1) local += __shfl_down(local, off);
    const int lane = tid & 63, wid = tid >> 6;
    if (lane == 0) red[wid] = local;
    __syncthreads();
    if (tid == 0) {
        float t = 0.f;
        #pragma unroll
        for (int k = 0; k < BLK / 64; ++k) t += red[k];
        out[b] = t;
    }
}

extern "C" void kernel_launch(void* const* d_in, const int* in_sizes, int n_in,
                              void* d_out, int out_size, void* d_ws, size_t ws_size,
                              hipStream_t stream) {
    const float* xr = (const float*)d_in[0];
    const float* xi = (const float*)d_in[1];
    const float* w  = (const float*)d_in[2];
    float* out = (float*)d_out;
    v2f* gg = (v2f*)d_ws;     // 70 gates x 8 v2f + 4 floats meas = 4496 B
    const int B = out_size;   // 512
    prep_kernel<<<1, 128, 0, stream>>>(w, gg);
    qsim_kernel<<<B, BLK, 0, stream>>>(xr, xi, gg, out);
}